// Round 10
// baseline (67.068 us; speedup 1.0000x reference)
//
#include <hip/hip_runtime.h>
#include <hip/hip_bf16.h>

#define BB 16
#define SS 512
#define HH 1024

typedef __attribute__((ext_vector_type(4))) float f32x4;
typedef __attribute__((ext_vector_type(8))) short bhalf8;

static __device__ __forceinline__ unsigned int pack2(float a, float b) {
    __hip_bfloat162 h = __float22bfloat162_rn(make_float2(a, b));
    union { __hip_bfloat162 h; unsigned int u; } cv;
    cv.h = h;
    return cv.u;
}

// ---------------------------------------------------------------------------
// Prepass (all coalesced):
//   blocks [0,2048):    W[e][k][d] -> Wt[e][d][k] bf16 via LDS transpose
//   blocks [2048,6144): hid f32 -> hidb bf16
// ---------------------------------------------------------------------------
__global__ __launch_bounds__(256)
void prep_kernel(const float* __restrict__ W, const float* __restrict__ hid,
                 const int* __restrict__ eidx, unsigned short* __restrict__ Wt,
                 unsigned short* __restrict__ hidb)
{
    int bid = blockIdx.x;
    int t = threadIdx.x;
    if (bid < 2048) {
        __shared__ float lds[32 * 132];
        int e  = bid >> 8;
        bool used = false;
        for (int b = 0; b < BB; ++b) used = used || (eidx[b] == e);
        if (!used) return;
        int rem = bid & 255;
        int kt = rem >> 3, dt = rem & 7;     // 32-k x 128-d tile
#pragma unroll
        for (int i = 0; i < 4; ++i) {
            int idx = t + i * 256;
            int row = idx >> 5, col4 = idx & 31;
            float4 v = *(const float4*)(W + ((size_t)e << 20)
                        + (size_t)(kt * 32 + row) * HH + dt * 128 + col4 * 4);
            float* dst = &lds[row * 132 + col4 * 4];
            dst[0] = v.x; dst[1] = v.y; dst[2] = v.z; dst[3] = v.w;
        }
        __syncthreads();
        int d = t >> 1, kh = t & 1;
        unsigned int u[8];
#pragma unroll
        for (int p = 0; p < 8; ++p) {
            float a = lds[(kh * 16 + p * 2)     * 132 + d];
            float b = lds[(kh * 16 + p * 2 + 1) * 132 + d];
            u[p] = pack2(a, b);
        }
        unsigned short* dst = Wt + ((size_t)e << 20)
                            + (size_t)(dt * 128 + d) * HH + kt * 32 + kh * 16;
        *reinterpret_cast<uint4*>(dst)     = make_uint4(u[0], u[1], u[2], u[3]);
        *reinterpret_cast<uint4*>(dst + 8) = make_uint4(u[4], u[5], u[6], u[7]);
    } else {
        int bid2 = bid - 2048;               // 2 rows per block
        int r = bid2 * 2 + (t >> 7);
        int col = (t & 127) * 8;
        const float* src = hid + (size_t)r * HH + col;
        float4 v0 = *(const float4*)(src);
        float4 v1 = *(const float4*)(src + 4);
        uint4 o;
        o.x = pack2(v0.x, v0.y); o.y = pack2(v0.z, v0.w);
        o.z = pack2(v1.x, v1.y); o.w = pack2(v1.z, v1.w);
        *reinterpret_cast<uint4*>(hidb + (size_t)r * HH + col) = o;
    }
}

// ---------------------------------------------------------------------------
// GEMM + fused bias+residual: x = hid @ W[e] + b[e] + inp -> d_out (f32).
// 256 blocks x 512 thr (8 waves, 4m x 2n of 64x64), tile 256x128, BK=32,
// quad-buffered LDS (96KB), ONE trailing {s_waitcnt vmcnt(N); s_barrier}
// per K-step (counted, never 0 until tail). Race-free proof: buf[(k-1)&3]
// reads are lgkm-retired before each wave reaches iter k-1's barrier, and
// stage(k+3) (issued in iter k, after that barrier) is the only writer.
// pair-line XOR LDS layout (verified 0 conflicts), mfma 16x16x32 bf16.
// ---------------------------------------------------------------------------
__global__ __launch_bounds__(512, 2)
void gemm8_kernel(const unsigned short* __restrict__ hidb,
                  const float* __restrict__ inp,
                  const int* __restrict__ eidx,
                  const unsigned short* __restrict__ Wt,
                  const float* __restrict__ bias,
                  float* __restrict__ out)
{
    __shared__ char ldsA[4 * 16384];   // A: bf16 [256 r][32 k] per buf
    __shared__ char ldsW[4 * 8192];    // W: bf16 [128 d][32 k] per buf

    int bx  = blockIdx.x;
    int swz = (bx & 7) * 32 + (bx >> 3);      // XCD-bijective (256 % 8 == 0)
    int bt   = swz >> 4;                      // batch 0..15
    int tile = swz & 15;
    int mt = tile >> 3, nt = tile & 7;        // 2 m-tiles x 8 n-tiles
    int e = eidx[bt];

    int t = threadIdx.x, wave = t >> 6, lane = t & 63;
    int l15 = lane & 15, g = lane >> 4;
    int wm = wave >> 1, wn = wave & 1;        // 4m x 2n, wave tile 64x64

    int brow = bt * SS + mt * 256;
    int ncol0 = nt * 128;

    // A: 1024 chunks of 16B (2/thread); W: 512 chunks (1/thread).
    // chunk c: line=c>>3, p=c&7, q=p^(line&7), row=2*line+(q>>2), s=q&3.
    const unsigned short* asrc[2];
    int aoff[2];
#pragma unroll
    for (int i = 0; i < 2; ++i) {
        int c = t + i * 512;
        int line = c >> 3, p = c & 7, q = p ^ (line & 7);
        int row = line * 2 + (q >> 2), s = q & 3;
        asrc[i] = hidb + (size_t)(brow + row) * HH + s * 8;
        aoff[i] = c * 16;
    }
    const unsigned short* wsrc;
    int woff;
    {
        int line = t >> 3, p = t & 7, q = p ^ (line & 7);
        int row = line * 2 + (q >> 2), s = q & 3;
        wsrc = Wt + ((size_t)e << 20) + (size_t)(ncol0 + row) * HH + s * 8;
        woff = t * 16;
    }

    auto stage = [&](int ks, int b) {
#pragma unroll
        for (int i = 0; i < 2; ++i)
            __builtin_amdgcn_global_load_lds(
                (const __attribute__((address_space(1))) void*)(asrc[i] + ks * 32),
                (__attribute__((address_space(3))) void*)(ldsA + b * 16384 + aoff[i]),
                16, 0, 0);
        __builtin_amdgcn_global_load_lds(
            (const __attribute__((address_space(1))) void*)(wsrc + ks * 32),
            (__attribute__((address_space(3))) void*)(ldsW + b * 8192 + woff),
            16, 0, 0);
    };

    f32x4 acc[4][4] = {};

    auto body = [&](int ks) {
        const char* Af = ldsA + (ks & 3) * 16384;
        const char* Wf = ldsW + (ks & 3) * 8192;
        bhalf8 af[4], bf[4];
#pragma unroll
        for (int mf = 0; mf < 4; ++mf) {
            int r = wm * 64 + mf * 16 + l15;
            int line = r >> 1;
            int p = (g + ((r & 1) << 2)) ^ (line & 7);
            af[mf] = *reinterpret_cast<const bhalf8*>(Af + line * 128 + p * 16);
        }
#pragma unroll
        for (int nf = 0; nf < 4; ++nf) {
            int d = wn * 64 + nf * 16 + l15;
            int line = d >> 1;
            int p = (g + ((d & 1) << 2)) ^ (line & 7);
            bf[nf] = *reinterpret_cast<const bhalf8*>(Wf + line * 128 + p * 16);
        }
        __builtin_amdgcn_s_setprio(1);
#pragma unroll
        for (int mf = 0; mf < 4; ++mf)
#pragma unroll
            for (int nf = 0; nf < 4; ++nf)
                acc[mf][nf] = __builtin_amdgcn_mfma_f32_16x16x32_bf16(
                    af[mf], bf[nf], acc[mf][nf], 0, 0, 0);
        __builtin_amdgcn_s_setprio(0);
    };

    // prologue: 3 stages in flight; wait for stage 0 (2 stages may remain)
    stage(0, 0); stage(1, 1); stage(2, 2);
    asm volatile("s_waitcnt vmcnt(6)" ::: "memory");
    __builtin_amdgcn_s_barrier();

    for (int ks = 0; ks < 32; ++ks) {
        if (ks <= 28) stage(ks + 3, (ks + 3) & 3);   // issue-early
        body(ks);
        if (ks < 29) {        // need buf[ks+1]: 2 stages may remain in flight
            asm volatile("s_waitcnt vmcnt(6)" ::: "memory");
            __builtin_amdgcn_s_barrier();
        } else if (ks == 29) {
            asm volatile("s_waitcnt vmcnt(3)" ::: "memory");
            __builtin_amdgcn_s_barrier();
        } else if (ks == 30) {
            asm volatile("s_waitcnt vmcnt(0)" ::: "memory");
            __builtin_amdgcn_s_barrier();
        }
    }

    // ---- epilogue: x = acc + bias[e] + inp; store f32 to d_out ----
#pragma unroll
    for (int nf = 0; nf < 4; ++nf) {
        int dcol = ncol0 + wn * 64 + nf * 16 + l15;
        float bv = bias[e * HH + dcol];
#pragma unroll
        for (int mf = 0; mf < 4; ++mf)
#pragma unroll
            for (int j = 0; j < 4; ++j) {
                int srow = brow + wm * 64 + mf * 16 + g * 4 + j;
                size_t off = (size_t)srow * HH + dcol;
                out[off] = acc[mf][nf][j] + bv + inp[off];
            }
    }
}

// ---------------------------------------------------------------------------
// Post: in-place LayerNorm over x (= d_out). One block per row, single pass.
// XCD-matched row permutation (gemm XCD x wrote rows [1024x, 1024x+1024)).
// ---------------------------------------------------------------------------
__global__ __launch_bounds__(256)
void post_kernel(float* __restrict__ x, const float* __restrict__ gamma,
                 const float* __restrict__ beta)
{
    int bid = blockIdx.x;
    int row = ((bid & 7) << 10) | (bid >> 3);   // XCD-matched (8192 = 8*1024)
    int t = threadIdx.x;

    size_t base = (size_t)row * HH + t * 4;
    float4 v = *reinterpret_cast<const float4*>(&x[base]);

    float s1 = v.x + v.y + v.z + v.w;
    float s2 = v.x * v.x + v.y * v.y + v.z * v.z + v.w * v.w;
#pragma unroll
    for (int off = 32; off > 0; off >>= 1) {
        s1 += __shfl_xor(s1, off, 64);
        s2 += __shfl_xor(s2, off, 64);
    }
    __shared__ float red[8];
    if ((t & 63) == 0) { red[(t >> 6) * 2] = s1; red[(t >> 6) * 2 + 1] = s2; }
    __syncthreads();
    float S1 = red[0] + red[2] + red[4] + red[6];
    float S2 = red[1] + red[3] + red[5] + red[7];
    float mu  = S1 * (1.0f / HH);
    float var = S2 * (1.0f / HH) - mu * mu;
    float rs = rsqrtf(var + 1e-12f);

    float4 gv = *reinterpret_cast<const float4*>(&gamma[t * 4]);
    float4 be = *reinterpret_cast<const float4*>(&beta[t * 4]);
    float4 o;
    o.x = (v.x - mu) * rs * gv.x + be.x;
    o.y = (v.y - mu) * rs * gv.y + be.y;
    o.z = (v.z - mu) * rs * gv.z + be.z;
    o.w = (v.w - mu) * rs * gv.w + be.w;
    *reinterpret_cast<float4*>(&x[base]) = o;
}

extern "C" void kernel_launch(void* const* d_in, const int* in_sizes, int n_in,
                              void* d_out, int out_size, void* d_ws, size_t ws_size,
                              hipStream_t stream) {
    const float* hid   = (const float*)d_in[0];
    const float* inp   = (const float*)d_in[1];
    const int*   eidx  = (const int*)d_in[2];
    const float* W     = (const float*)d_in[3];
    const float* bias  = (const float*)d_in[4];
    const float* gamma = (const float*)d_in[5];
    const float* beta  = (const float*)d_in[6];
    float* out = (float*)d_out;

    unsigned short* Wt   = (unsigned short*)d_ws;                        // 16 MiB
    unsigned short* hidb = (unsigned short*)((char*)d_ws + (16u << 20)); // 16 MiB

    prep_kernel<<<6144, 256, 0, stream>>>(W, hid, eidx, Wt, hidb);
    gemm8_kernel<<<256, 512, 0, stream>>>(hidb, inp, eidx, Wt, bias, out);
    post_kernel<<<BB * SS, 256, 0, stream>>>(out, gamma, beta);
}

// Round 11
// 67.031 us; speedup vs baseline: 1.0006x; 1.0006x over previous
//
#include <hip/hip_runtime.h>
#include <hip/hip_bf16.h>

#define BB 16
#define SS 512
#define HH 1024

typedef __attribute__((ext_vector_type(4))) float f32x4;
typedef __attribute__((ext_vector_type(8))) short bhalf8;

static __device__ __forceinline__ unsigned int pack2(float a, float b) {
    __hip_bfloat162 h = __float22bfloat162_rn(make_float2(a, b));
    union { __hip_bfloat162 h; unsigned int u; } cv;
    cv.h = h;
    return cv.u;
}

// ---------------------------------------------------------------------------
// Prepass (all coalesced):
//   blocks [0,2048):    W[e][k][d] -> Wt[e][d][k] bf16 via LDS transpose
//   blocks [2048,6144): hid f32 -> hidb bf16
// ---------------------------------------------------------------------------
__global__ __launch_bounds__(256)
void prep_kernel(const float* __restrict__ W, const float* __restrict__ hid,
                 const int* __restrict__ eidx, unsigned short* __restrict__ Wt,
                 unsigned short* __restrict__ hidb)
{
    int bid = blockIdx.x;
    int t = threadIdx.x;
    if (bid < 2048) {
        __shared__ float lds[32 * 132];
        int e  = bid >> 8;
        bool used = false;
        for (int b = 0; b < BB; ++b) used = used || (eidx[b] == e);
        if (!used) return;
        int rem = bid & 255;
        int kt = rem >> 3, dt = rem & 7;     // 32-k x 128-d tile
#pragma unroll
        for (int i = 0; i < 4; ++i) {
            int idx = t + i * 256;
            int row = idx >> 5, col4 = idx & 31;
            float4 v = *(const float4*)(W + ((size_t)e << 20)
                        + (size_t)(kt * 32 + row) * HH + dt * 128 + col4 * 4);
            float* dst = &lds[row * 132 + col4 * 4];
            dst[0] = v.x; dst[1] = v.y; dst[2] = v.z; dst[3] = v.w;
        }
        __syncthreads();
        int d = t >> 1, kh = t & 1;
        unsigned int u[8];
#pragma unroll
        for (int p = 0; p < 8; ++p) {
            float a = lds[(kh * 16 + p * 2)     * 132 + d];
            float b = lds[(kh * 16 + p * 2 + 1) * 132 + d];
            u[p] = pack2(a, b);
        }
        unsigned short* dst = Wt + ((size_t)e << 20)
                            + (size_t)(dt * 128 + d) * HH + kt * 32 + kh * 16;
        *reinterpret_cast<uint4*>(dst)     = make_uint4(u[0], u[1], u[2], u[3]);
        *reinterpret_cast<uint4*>(dst + 8) = make_uint4(u[4], u[5], u[6], u[7]);
    } else {
        int bid2 = bid - 2048;               // 2 rows per block
        int r = bid2 * 2 + (t >> 7);
        int col = (t & 127) * 8;
        const float* src = hid + (size_t)r * HH + col;
        float4 v0 = *(const float4*)(src);
        float4 v1 = *(const float4*)(src + 4);
        uint4 o;
        o.x = pack2(v0.x, v0.y); o.y = pack2(v0.z, v0.w);
        o.z = pack2(v1.x, v1.y); o.w = pack2(v1.z, v1.w);
        *reinterpret_cast<uint4*>(hidb + (size_t)r * HH + col) = o;
    }
}

// ---------------------------------------------------------------------------
// GEMM + fused bias+residual: x = hid @ W[e] + b[e] + inp -> d_out (f32).
// 256 blocks x 512 thr (8 waves, 4m x 2n of 64x64), tile 256x128, BK=32,
// quad-buffered LDS (96KB), ONE trailing {s_waitcnt vmcnt(N); s_barrier}
// per K-step (counted, never 0 until tail). Race-free proof: buf[(k-1)&3]
// reads are lgkm-retired before each wave reaches iter k-1's barrier, and
// stage(k+3) (issued in iter k, after that barrier) is the only writer.
// pair-line XOR LDS layout (verified 0 conflicts), mfma 16x16x32 bf16.
// ---------------------------------------------------------------------------
__global__ __launch_bounds__(512, 2)
void gemm8_kernel(const unsigned short* __restrict__ hidb,
                  const float* __restrict__ inp,
                  const int* __restrict__ eidx,
                  const unsigned short* __restrict__ Wt,
                  const float* __restrict__ bias,
                  float* __restrict__ out)
{
    __shared__ char ldsA[4 * 16384];   // A: bf16 [256 r][32 k] per buf
    __shared__ char ldsW[4 * 8192];    // W: bf16 [128 d][32 k] per buf

    int bx  = blockIdx.x;
    int swz = (bx & 7) * 32 + (bx >> 3);      // XCD-bijective (256 % 8 == 0)
    int bt   = swz >> 4;                      // batch 0..15
    int tile = swz & 15;
    int mt = tile >> 3, nt = tile & 7;        // 2 m-tiles x 8 n-tiles
    int e = eidx[bt];

    int t = threadIdx.x, wave = t >> 6, lane = t & 63;
    int l15 = lane & 15, g = lane >> 4;
    int wm = wave >> 1, wn = wave & 1;        // 4m x 2n, wave tile 64x64

    int brow = bt * SS + mt * 256;
    int ncol0 = nt * 128;

    // A: 1024 chunks of 16B (2/thread); W: 512 chunks (1/thread).
    // chunk c: line=c>>3, p=c&7, q=p^(line&7), row=2*line+(q>>2), s=q&3.
    const unsigned short* asrc[2];
    int aoff[2];
#pragma unroll
    for (int i = 0; i < 2; ++i) {
        int c = t + i * 512;
        int line = c >> 3, p = c & 7, q = p ^ (line & 7);
        int row = line * 2 + (q >> 2), s = q & 3;
        asrc[i] = hidb + (size_t)(brow + row) * HH + s * 8;
        aoff[i] = c * 16;
    }
    const unsigned short* wsrc;
    int woff;
    {
        int line = t >> 3, p = t & 7, q = p ^ (line & 7);
        int row = line * 2 + (q >> 2), s = q & 3;
        wsrc = Wt + ((size_t)e << 20) + (size_t)(ncol0 + row) * HH + s * 8;
        woff = t * 16;
    }

    auto stage = [&](int ks, int b) {
#pragma unroll
        for (int i = 0; i < 2; ++i)
            __builtin_amdgcn_global_load_lds(
                (const __attribute__((address_space(1))) void*)(asrc[i] + ks * 32),
                (__attribute__((address_space(3))) void*)(ldsA + b * 16384 + aoff[i]),
                16, 0, 0);
        __builtin_amdgcn_global_load_lds(
            (const __attribute__((address_space(1))) void*)(wsrc + ks * 32),
            (__attribute__((address_space(3))) void*)(ldsW + b * 8192 + woff),
            16, 0, 0);
    };

    f32x4 acc[4][4] = {};

    auto body = [&](int ks) {
        const char* Af = ldsA + (ks & 3) * 16384;
        const char* Wf = ldsW + (ks & 3) * 8192;
        bhalf8 af[4], bf[4];
#pragma unroll
        for (int mf = 0; mf < 4; ++mf) {
            int r = wm * 64 + mf * 16 + l15;
            int line = r >> 1;
            int p = (g + ((r & 1) << 2)) ^ (line & 7);
            af[mf] = *reinterpret_cast<const bhalf8*>(Af + line * 128 + p * 16);
        }
#pragma unroll
        for (int nf = 0; nf < 4; ++nf) {
            int d = wn * 64 + nf * 16 + l15;
            int line = d >> 1;
            int p = (g + ((d & 1) << 2)) ^ (line & 7);
            bf[nf] = *reinterpret_cast<const bhalf8*>(Wf + line * 128 + p * 16);
        }
        __builtin_amdgcn_s_setprio(1);
#pragma unroll
        for (int mf = 0; mf < 4; ++mf)
#pragma unroll
            for (int nf = 0; nf < 4; ++nf)
                acc[mf][nf] = __builtin_amdgcn_mfma_f32_16x16x32_bf16(
                    af[mf], bf[nf], acc[mf][nf], 0, 0, 0);
        __builtin_amdgcn_s_setprio(0);
    };

    // prologue: 3 stages in flight; wait for stage 0 (2 stages may remain)
    stage(0, 0); stage(1, 1); stage(2, 2);
    asm volatile("s_waitcnt vmcnt(6)" ::: "memory");
    __builtin_amdgcn_s_barrier();

    for (int ks = 0; ks < 32; ++ks) {
        if (ks <= 28) stage(ks + 3, (ks + 3) & 3);   // issue-early
        body(ks);
        if (ks < 29) {        // need buf[ks+1]: 2 stages may remain in flight
            asm volatile("s_waitcnt vmcnt(6)" ::: "memory");
            __builtin_amdgcn_s_barrier();
        } else if (ks == 29) {
            asm volatile("s_waitcnt vmcnt(3)" ::: "memory");
            __builtin_amdgcn_s_barrier();
        } else if (ks == 30) {
            asm volatile("s_waitcnt vmcnt(0)" ::: "memory");
            __builtin_amdgcn_s_barrier();
        }
    }

    // ---- epilogue: x = acc + bias[e] + inp; store f32 to d_out ----
#pragma unroll
    for (int nf = 0; nf < 4; ++nf) {
        int dcol = ncol0 + wn * 64 + nf * 16 + l15;
        float bv = bias[e * HH + dcol];
#pragma unroll
        for (int mf = 0; mf < 4; ++mf)
#pragma unroll
            for (int j = 0; j < 4; ++j) {
                int srow = brow + wm * 64 + mf * 16 + g * 4 + j;
                size_t off = (size_t)srow * HH + dcol;
                out[off] = acc[mf][nf][j] + bv + inp[off];
            }
    }
}

// ---------------------------------------------------------------------------
// Post: in-place LayerNorm over x (= d_out). One block per row, single pass.
// XCD-matched row permutation (gemm XCD x wrote rows [1024x, 1024x+1024)).
// ---------------------------------------------------------------------------
__global__ __launch_bounds__(256)
void post_kernel(float* __restrict__ x, const float* __restrict__ gamma,
                 const float* __restrict__ beta)
{
    int bid = blockIdx.x;
    int row = ((bid & 7) << 10) | (bid >> 3);   // XCD-matched (8192 = 8*1024)
    int t = threadIdx.x;

    size_t base = (size_t)row * HH + t * 4;
    float4 v = *reinterpret_cast<const float4*>(&x[base]);

    float s1 = v.x + v.y + v.z + v.w;
    float s2 = v.x * v.x + v.y * v.y + v.z * v.z + v.w * v.w;
#pragma unroll
    for (int off = 32; off > 0; off >>= 1) {
        s1 += __shfl_xor(s1, off, 64);
        s2 += __shfl_xor(s2, off, 64);
    }
    __shared__ float red[8];
    if ((t & 63) == 0) { red[(t >> 6) * 2] = s1; red[(t >> 6) * 2 + 1] = s2; }
    __syncthreads();
    float S1 = red[0] + red[2] + red[4] + red[6];
    float S2 = red[1] + red[3] + red[5] + red[7];
    float mu  = S1 * (1.0f / HH);
    float var = S2 * (1.0f / HH) - mu * mu;
    float rs = rsqrtf(var + 1e-12f);

    float4 gv = *reinterpret_cast<const float4*>(&gamma[t * 4]);
    float4 be = *reinterpret_cast<const float4*>(&beta[t * 4]);
    float4 o;
    o.x = (v.x - mu) * rs * gv.x + be.x;
    o.y = (v.y - mu) * rs * gv.y + be.y;
    o.z = (v.z - mu) * rs * gv.z + be.z;
    o.w = (v.w - mu) * rs * gv.w + be.w;
    *reinterpret_cast<float4*>(&x[base]) = o;
}

extern "C" void kernel_launch(void* const* d_in, const int* in_sizes, int n_in,
                              void* d_out, int out_size, void* d_ws, size_t ws_size,
                              hipStream_t stream) {
    const float* hid   = (const float*)d_in[0];
    const float* inp   = (const float*)d_in[1];
    const int*   eidx  = (const int*)d_in[2];
    const float* W     = (const float*)d_in[3];
    const float* bias  = (const float*)d_in[4];
    const float* gamma = (const float*)d_in[5];
    const float* beta  = (const float*)d_in[6];
    float* out = (float*)d_out;

    unsigned short* Wt   = (unsigned short*)d_ws;                        // 16 MiB
    unsigned short* hidb = (unsigned short*)((char*)d_ws + (16u << 20)); // 16 MiB

    prep_kernel<<<6144, 256, 0, stream>>>(W, hid, eidx, Wt, hidb);
    gemm8_kernel<<<256, 512, 0, stream>>>(hidb, inp, eidx, Wt, bias, out);
    post_kernel<<<BB * SS, 256, 0, stream>>>(out, gamma, beta);
}